// Round 1
// baseline (195.939 us; speedup 1.0000x reference)
//
#include <hip/hip_runtime.h>

#define STEPS   2000
#define DT_F    0.001f
#define EPS_F   1e-6f
#define MAXT_F  2.0f
#define KPRE    16

__global__ __launch_bounds__(256) void ddm_sim_kernel(
    const float* __restrict__ x,
    const float* __restrict__ noise,
    const float* __restrict__ p_a,
    const float* __restrict__ p_z,
    const float* __restrict__ p_ndt,
    const float* __restrict__ p_dg,
    float* __restrict__ out,   // [0,n) = pred_rt, [n,2n) = pred_choice
    int n)
{
    const int i = blockIdx.x * blockDim.x + threadIdx.x;
    if (i >= n) return;

    const float a    = *p_a;
    const float z    = *p_z;
    const float ndt  = *p_ndt;
    const float dg   = *p_dg;

    // drift = drift_gain * x[i]; per-step increment pieces, rounding pinned
    const float drift    = __fmul_rn(dg, x[i]);
    const float drift_dt = __fmul_rn(drift, DT_F);
    const float nscale   = __fsqrt_rn(DT_F);        // SIGMA(=1) * sqrt(DT), f32
    const float a_hi     = __fsub_rn(a, EPS_F);     //  a - EPS
    const float a_lo     = __fsub_rn(EPS_F, a);     // -a + EPS

    float dv     = __fmul_rn(z, a);
    float rt     = 0.0f;
    float choice = 0.0f;
    bool  act    = true;

    const float*  p      = noise + i;
    const size_t  stride = (size_t)n;

    // register double-buffered prefetch, depth KPRE
    float buf[KPRE];
#pragma unroll
    for (int k = 0; k < KPRE; ++k) buf[k] = p[(size_t)k * stride];

    int t = 0;
    while (true) {
        const int tn = t + KPRE;
        float nbuf[KPRE];
        if (tn < STEPS) {
            const float* pn = p + (size_t)tn * stride;
#pragma unroll
            for (int k = 0; k < KPRE; ++k)
                nbuf[k] = act ? pn[(size_t)k * stride] : 0.0f;
        } else {
#pragma unroll
            for (int k = 0; k < KPRE; ++k) nbuf[k] = 0.0f;
        }

#pragma unroll
        for (int k = 0; k < KPRE; ++k) {
            if (act) {
                // dv = (dv + drift*DT) + nscale*nz  -- exact ref op order, no FMA
                dv = __fadd_rn(__fadd_rn(dv, drift_dt), __fmul_rn(nscale, buf[k]));
                const bool up = (dv >= a_hi);
                const bool lo = (dv <= a_lo);
                if (up || lo) {
                    rt     = __fadd_rn(__fmul_rn((float)(t + k), DT_F), ndt);
                    choice = up ? 1.0f : 0.0f;
                    act    = false;
                }
            }
        }

        t = tn;
        if (t >= STEPS) break;
        if (!__any(act)) break;   // whole wave done -> skip remaining rows

#pragma unroll
        for (int k = 0; k < KPRE; ++k) buf[k] = nbuf[k];
    }

    out[i]     = act ? __fadd_rn(MAXT_F, ndt) : rt;      // pred_rt
    out[n + i] = act ? 0.5f : choice;                     // pred_choice
}

extern "C" void kernel_launch(void* const* d_in, const int* in_sizes, int n_in,
                              void* d_out, int out_size, void* d_ws, size_t ws_size,
                              hipStream_t stream) {
    const float* x     = (const float*)d_in[0];
    const float* noise = (const float*)d_in[1];
    const float* a     = (const float*)d_in[2];
    const float* z     = (const float*)d_in[3];
    const float* ndt   = (const float*)d_in[4];
    const float* dg    = (const float*)d_in[5];
    float* out = (float*)d_out;

    const int n = in_sizes[0];              // 65536 trials
    const int block = 256;
    const int grid  = (n + block - 1) / block;
    ddm_sim_kernel<<<grid, block, 0, stream>>>(x, noise, a, z, ndt, dg, out, n);
}

// Round 2
// 118.254 us; speedup vs baseline: 1.6569x; 1.6569x over previous
//
#include <hip/hip_runtime.h>

#define STEPS   2000
#define DT_F    0.001f
#define EPS_F   1e-6f
#define MAXT_F  2.0f
#define CHUNK   16
#define NCHUNK  (STEPS / CHUNK)   // 125
// 6 rotating register buffers -> prefetch distance 5 chunks (80 loads in flight)

// Prefetch one chunk of noise rows into a register buffer. Chunk index is
// clamped (re-reads last chunk near the end) so the load sequence is
// branch-free and the compiler can emit precise counted s_waitcnt vmcnt(N).
#define LOADC(BUF, c_) do {                                                   \
    const int cc = ((c_) < (NCHUNK - 1)) ? (c_) : (NCHUNK - 1);               \
    const float* bp = p + (size_t)cc * (size_t)CHUNK * stride;                \
    _Pragma("unroll")                                                         \
    for (int k = 0; k < CHUNK; ++k) BUF[k] = bp[(size_t)k * stride];          \
} while (0)

// Advance the simulation CHUNK steps using a loaded buffer. Exact reference
// rounding: dv = ((dv + drift*DT) + nscale*nz), separate mul/add, no FMA.
// dv is NOT frozen after the hit (it's dead once rt/choice latch; act blocks
// any further latch) -- saves a cndmask per step.
#define STEPC(BUF, cbase) do {                                                \
    _Pragma("unroll")                                                         \
    for (int k = 0; k < CHUNK; ++k) {                                         \
        dv = __fadd_rn(__fadd_rn(dv, drift_dt), __fmul_rn(nscale, BUF[k]));   \
        const bool up = (dv >= a_hi);                                         \
        const bool lo = (dv <= a_lo);                                         \
        if (act && (up || lo)) {                                              \
            rt     = __fadd_rn(__fmul_rn((float)((cbase) * CHUNK + k), DT_F), \
                               ndt);                                          \
            choice = up ? 1.0f : 0.0f;                                        \
            act    = false;                                                   \
        }                                                                     \
    }                                                                         \
} while (0)

__global__ __launch_bounds__(256, 1) void ddm_sim_kernel(
    const float* __restrict__ x,
    const float* __restrict__ noise,
    const float* __restrict__ p_a,
    const float* __restrict__ p_z,
    const float* __restrict__ p_ndt,
    const float* __restrict__ p_dg,
    float* __restrict__ out,   // [0,n) = pred_rt, [n,2n) = pred_choice
    int n)
{
    const int i = blockIdx.x * blockDim.x + threadIdx.x;
    if (i >= n) return;

    const float a   = *p_a;
    const float z   = *p_z;
    const float ndt = *p_ndt;
    const float dg  = *p_dg;

    const float drift    = __fmul_rn(dg, x[i]);
    const float drift_dt = __fmul_rn(drift, DT_F);
    const float nscale   = __fsqrt_rn(DT_F);      // SIGMA(=1) * sqrt(DT)
    const float a_hi     = __fsub_rn(a, EPS_F);   //  a - EPS
    const float a_lo     = __fsub_rn(EPS_F, a);   // -a + EPS

    float dv     = __fmul_rn(z, a);
    float rt     = 0.0f;
    float choice = 0.0f;
    bool  act    = true;

    const float* p      = noise + i;
    const size_t stride = (size_t)n;

    float B0[CHUNK], B1[CHUNK], B2[CHUNK], B3[CHUNK], B4[CHUNK], B5[CHUNK];

    // prologue: fill pipeline 5 deep
    LOADC(B0, 0);
    LOADC(B1, 1);
    LOADC(B2, 2);
    LOADC(B3, 3);
    LOADC(B4, 4);

    int c = 0;
    while (true) {
        LOADC(B5, c + 5); STEPC(B0, c); ++c; if (c >= NCHUNK || !__any(act)) break;
        LOADC(B0, c + 5); STEPC(B1, c); ++c; if (c >= NCHUNK || !__any(act)) break;
        LOADC(B1, c + 5); STEPC(B2, c); ++c; if (c >= NCHUNK || !__any(act)) break;
        LOADC(B2, c + 5); STEPC(B3, c); ++c; if (c >= NCHUNK || !__any(act)) break;
        LOADC(B3, c + 5); STEPC(B4, c); ++c; if (c >= NCHUNK || !__any(act)) break;
        LOADC(B4, c + 5); STEPC(B5, c); ++c; if (c >= NCHUNK || !__any(act)) break;
    }

    out[i]     = act ? __fadd_rn(MAXT_F, ndt) : rt;   // pred_rt
    out[n + i] = act ? 0.5f : choice;                 // pred_choice
}

extern "C" void kernel_launch(void* const* d_in, const int* in_sizes, int n_in,
                              void* d_out, int out_size, void* d_ws, size_t ws_size,
                              hipStream_t stream) {
    const float* x     = (const float*)d_in[0];
    const float* noise = (const float*)d_in[1];
    const float* a     = (const float*)d_in[2];
    const float* z     = (const float*)d_in[3];
    const float* ndt   = (const float*)d_in[4];
    const float* dg    = (const float*)d_in[5];
    float* out = (float*)d_out;

    const int n = in_sizes[0];              // 65536 trials
    const int block = 256;
    const int grid  = (n + block - 1) / block;
    ddm_sim_kernel<<<grid, block, 0, stream>>>(x, noise, a, z, ndt, dg, out, n);
}